// Round 18
// baseline (135.463 us; speedup 1.0000x reference)
//
#include <hip/hip_runtime.h>
#include <cstdint>
#include <cstddef>

#define N_NODES  50000
#define N_EDGES  800000
#define DIM      128
#define N_GRAPHS 64
#define NB       196       // coarse buckets of 256 nodes
#define BSH      8
#define EPB      2048      // edges per k_bucket block
#define BPAD     16        // cursor padding: one counter per 64B line
#define NREP     4         // cursor replicas per bucket (r18: kill flush convoy)
#define SEG      2048      // per-replica segment capacity
#define CAP      (NREP*SEG) // per-bucket region capacity
#define NBB      391       // bucket blocks = ceil(N_EDGES/EPB)
#define NPREP    1579      // prep blocks = ceil((N_NODES*16 + 8192)/512)

typedef __attribute__((ext_vector_type(8))) short     bf16x8;
typedef __attribute__((ext_vector_type(4))) float     f32x4;

__device__ __forceinline__ int clamp_node(int v) {
    return v < 0 ? 0 : (v >= N_NODES ? N_NODES - 1 : v);
}
__device__ __forceinline__ unsigned short f2bf(float f) {
    union { float f; unsigned u; } v; v.f = f;
    unsigned r = v.u + 0x7FFF + ((v.u >> 16) & 1);   // round-to-nearest-even
    return (unsigned short)(r >> 16);
}
__device__ __forceinline__ float bflo(unsigned u) {
    union { unsigned u; float f; } v; v.u = u << 16; return v.f;
}
__device__ __forceinline__ float bfhi(unsigned u) {
    union { unsigned u; float f; } v; v.u = u & 0xFFFF0000u; return v.f;
}

// ---------------------------------------------------------------------------
// Front kernel — two block roles (block-granular divergence):
//  blocks [0,NBB):        LDS counting sort of 2048 edges into 196 coarse
//                         buckets; bulk-append runs into fixed per-bucket
//                         SEGMENTS tmp[b*CAP + rep*SEG ..] where rep =
//                         blockIdx&3. 4 cursor replicas per bucket, each on
//                         its own 64B line: per-line atomic demand 391 -> ~98
//                         (r17 analysis: single cursor = 391 serialized RMWs
//                         x 40ns = 15.6us flush floor). Staggered flush order
//                         (r7 lesson) retained.
//  blocks [NBB,NBB+NPREP): f32->bf16 feature convert + MFMA-order weight
//                         packs (streams concurrently with bucket tail).
// Packed entry: src (16b) | dst_local (8b) << 16.
// ---------------------------------------------------------------------------
__global__ __launch_bounds__(512) void k_front(const int* __restrict__ ei,
                                               int* __restrict__ bcur,
                                               unsigned* __restrict__ tmp,
                                               const float* __restrict__ x,
                                               unsigned short* __restrict__ xb,
                                               const float* __restrict__ W1l,
                                               const float* __restrict__ W1r,
                                               const float* __restrict__ W2l,
                                               const float* __restrict__ W2r,
                                               unsigned short* __restrict__ wbuf1,
                                               unsigned short* __restrict__ wbuf2) {
    int t = threadIdx.x;

    if (blockIdx.x >= NBB) {
        // ---------------- prep role ----------------
        int i = (blockIdx.x - NBB) * 512 + t;
        const int n8 = N_NODES * 16;            // 800000 8-elem conversions
        if (i < n8) {
            const float4* p = (const float4*)(x + (size_t)i * 8);
            float4 a = p[0], b = p[1];
            union { unsigned short s[8]; uint4 u; } o;
            o.s[0] = f2bf(a.x); o.s[1] = f2bf(a.y); o.s[2] = f2bf(a.z); o.s[3] = f2bf(a.w);
            o.s[4] = f2bf(b.x); o.s[5] = f2bf(b.y); o.s[6] = f2bf(b.z); o.s[7] = f2bf(b.w);
            *(uint4*)(xb + (size_t)i * 8) = o.u;
            return;
        }
        int tid = i - n8;
        if (tid >= 2 * 8 * 8 * 64) return;
        int which = tid >> 12;
        int id    = tid & 4095;
        const float* Wl = which ? W2l : W1l;
        const float* Wr = which ? W2r : W1r;
        unsigned short* wbuf = which ? wbuf2 : wbuf1;
        int lane = id & 63;
        int ks   = (id >> 6) & 7;
        int ot   = id >> 9;
        int o  = ot * 16 + (lane & 15);
        int kb = ks * 32 + ((lane >> 4) << 3);
        union { unsigned short s[8]; uint4 u; } frag;
        #pragma unroll
        for (int j = 0; j < 8; ++j) {
            int k = kb + j;
            float v = (k < DIM) ? Wl[o * DIM + k] : Wr[o * DIM + (k - DIM)];
            frag.s[j] = f2bf(v);
        }
        *(uint4*)(wbuf + (size_t)id * 8) = frag.u;
        return;
    }

    // ---------------- bucket role ----------------
    __shared__ int cnt[256], cur[256], ofs[256];
    __shared__ int s[512];
    __shared__ unsigned list[EPB];
    int base = blockIdx.x * EPB;
    int eend = base + EPB; if (eend > N_EDGES) eend = N_EDGES;

    if (t < 256) cnt[t] = 0;
    __syncthreads();

    int d[4], sv[4];
    bool ok[4];
    #pragma unroll
    for (int i = 0; i < 4; ++i) {
        int e = base + t + i * 512;
        ok[i] = (e < eend);
        if (ok[i]) {
            d[i]  = clamp_node(ei[N_EDGES + e]);
            sv[i] = clamp_node(ei[e]);
            atomicAdd(&cnt[d[i] >> BSH], 1);
        }
    }
    __syncthreads();
    int v = (t < 256) ? cnt[t] : 0;
    s[t] = v;
    __syncthreads();
    for (int off = 1; off < 256; off <<= 1) {
        int y = (t >= off && t < 256) ? s[t - off] : 0;
        __syncthreads();
        if (t < 256) s[t] += y;
        __syncthreads();
    }
    if (t < 256) { ofs[t] = s[t] - v; cur[t] = s[t] - v; }
    __syncthreads();
    #pragma unroll
    for (int i = 0; i < 4; ++i) {
        if (ok[i]) {
            int b = d[i] >> BSH;
            int p = atomicAdd(&cur[b], 1);
            list[p] = (unsigned)sv[i] | ((unsigned)(d[i] & 255) << 16);
        }
    }
    __syncthreads();
    int wv = t >> 6, lane = t & 63;
    int rep = blockIdx.x & (NREP - 1);
    const int NGRP = 25;   // ceil(196/8)
    for (int jj = 0; jj < NGRP; ++jj) {
        int b = wv + 8 * ((jj + (int)blockIdx.x) % NGRP);
        if (b >= NB) continue;
        int c = cnt[b];
        if (c == 0) continue;
        int gpos;
        if (lane == 0) gpos = atomicAdd(&bcur[(b * NREP + rep) * BPAD], c);
        gpos = __shfl(gpos, 0);
        if (gpos + c > SEG) c = (gpos < SEG) ? (SEG - gpos) : 0;  // defensive
        int ls = ofs[b];
        unsigned* dst = tmp + (size_t)b * CAP + (size_t)rep * SEG + gpos;
        for (int i = lane; i < c; i += 64) dst[i] = list[ls + i];
    }
}

// ---------------------------------------------------------------------------
// Local CSR build: one block per bucket. LDS 256-node histogram over the
// bucket's 4 segments -> scan -> per-node {start,end} (rsse, int2) -> scatter
// srcs into node order within the bucket's exclusive region. Also zeroes gsum.
// ---------------------------------------------------------------------------
__global__ __launch_bounds__(512) void k_csr(const unsigned* __restrict__ tmp,
                                             const int* __restrict__ bcur,
                                             int2* __restrict__ rsse,
                                             int* __restrict__ srcs,
                                             float* __restrict__ gsum) {
    __shared__ int lh[256], lcur[256];
    __shared__ int s[512];
    __shared__ int segc[NREP];
    int b = blockIdx.x;
    int t = threadIdx.x;
    size_t base = (size_t)b * CAP;

    if (t < NREP) {
        int c = bcur[(b * NREP + t) * BPAD];
        segc[t] = (c > SEG) ? SEG : c;
    }
    int gi = b * 512 + t;
    if (gi < N_GRAPHS * DIM) gsum[gi] = 0.f;

    if (t < 256) lh[t] = 0;
    __syncthreads();
    #pragma unroll
    for (int r = 0; r < NREP; ++r) {
        int nc = segc[r];
        const unsigned* seg = tmp + base + (size_t)r * SEG;
        for (int e = t; e < nc; e += 512)
            atomicAdd(&lh[seg[e] >> 16], 1);
    }
    __syncthreads();
    int v = (t < 256) ? lh[t] : 0;
    s[t] = v;
    __syncthreads();
    for (int off = 1; off < 256; off <<= 1) {
        int y = (t >= off && t < 256) ? s[t - off] : 0;
        __syncthreads();
        if (t < 256) s[t] += y;
        __syncthreads();
    }
    if (t < 256) {
        int st = s[t] - v;                 // exclusive local start
        lcur[t] = st;
        int node = (b << BSH) + t;
        if (node < N_NODES) rsse[node] = make_int2((int)base + st, (int)base + st + v);
    }
    __syncthreads();
    #pragma unroll
    for (int r = 0; r < NREP; ++r) {
        int nc = segc[r];
        const unsigned* seg = tmp + base + (size_t)r * SEG;
        for (int e = t; e < nc; e += 512) {
            unsigned val = seg[e];
            int pos = atomicAdd(&lcur[val >> 16], 1);
            srcs[base + pos] = (int)(val & 0xFFFFu);
        }
    }
}

// ---------------------------------------------------------------------------
// FUSED SAGE layer — FROZEN r15 gather/MFMA core (43.6us, VGPR 64; the gather
// is at the random-line service-rate roofline — concurrency 32/48/60, VGPR
// 32-88, two L2 restructures all ≥43.6us). Gather 12-edge unroll; B-frags
// inside the MFMA loop from hot 8KB wbuf; root A-frags after the barrier.
// POOL=1 (conv2): global_mean_pool stage 1 folded into the epilogue (r17:
// -14us; no h2 materialization; pools pre-bf16-round f32).
// ---------------------------------------------------------------------------
template<int POOL>
__global__ __launch_bounds__(256) void k_sage(const unsigned short* __restrict__ feat,
                                              const unsigned short* __restrict__ in2b,
                                              const int2* __restrict__ rsse,
                                              const int* __restrict__ srcs,
                                              const unsigned short* __restrict__ wbuf,
                                              const float* __restrict__ bias,
                                              unsigned short* __restrict__ outb,
                                              const int* __restrict__ batch,
                                              float* __restrict__ gsum) {
    __shared__ unsigned short almp[16][136];   // row stride 272B
    __shared__ int sb[16];
    int t    = threadIdx.x;
    int wave = t >> 6;
    int lane = t & 63;
    int n0   = blockIdx.x * 16;

    if (POOL && t < 16) sb[t] = batch[n0 + t];

    // ---- phase 1: gather-mean; lane (q,sub) owns node q's 16B chunk sub ----
    {
        int q   = lane >> 4;
        int sub = lane & 15;
        int node  = n0 + wave * 4 + q;
        int2 se   = rsse[node];
        int start = se.x;
        int end   = se.y;
        float a0 = 0.f, a1 = 0.f, a2 = 0.f, a3 = 0.f;
        float a4 = 0.f, a5 = 0.f, a6 = 0.f, a7 = 0.f;
        const size_t coff = (size_t)sub * 8;

#define ACC8(r) { a0 += bflo(r.x); a1 += bfhi(r.x); a2 += bflo(r.y); a3 += bfhi(r.y); \
                  a4 += bflo(r.z); a5 += bfhi(r.z); a6 += bflo(r.w); a7 += bfhi(r.w); }
        int e = start;
        for (; e + 12 <= end; e += 12) {
            int s0 = srcs[e + 0], s1 = srcs[e + 1], s2 = srcs[e + 2];
            int s3 = srcs[e + 3], s4 = srcs[e + 4], s5 = srcs[e + 5];
            int s6 = srcs[e + 6], s7 = srcs[e + 7], s8 = srcs[e + 8];
            int s9 = srcs[e + 9], s10 = srcs[e + 10], s11 = srcs[e + 11];
            uint4 r0  = *(const uint4*)(feat + (size_t)s0  * DIM + coff);
            uint4 r1  = *(const uint4*)(feat + (size_t)s1  * DIM + coff);
            uint4 r2  = *(const uint4*)(feat + (size_t)s2  * DIM + coff);
            uint4 r3  = *(const uint4*)(feat + (size_t)s3  * DIM + coff);
            uint4 r4  = *(const uint4*)(feat + (size_t)s4  * DIM + coff);
            uint4 r5  = *(const uint4*)(feat + (size_t)s5  * DIM + coff);
            uint4 r6  = *(const uint4*)(feat + (size_t)s6  * DIM + coff);
            uint4 r7  = *(const uint4*)(feat + (size_t)s7  * DIM + coff);
            uint4 r8  = *(const uint4*)(feat + (size_t)s8  * DIM + coff);
            uint4 r9  = *(const uint4*)(feat + (size_t)s9  * DIM + coff);
            uint4 r10 = *(const uint4*)(feat + (size_t)s10 * DIM + coff);
            uint4 r11 = *(const uint4*)(feat + (size_t)s11 * DIM + coff);
            ACC8(r0) ACC8(r1) ACC8(r2) ACC8(r3) ACC8(r4) ACC8(r5)
            ACC8(r6) ACC8(r7) ACC8(r8) ACC8(r9) ACC8(r10) ACC8(r11)
        }
        for (; e + 4 <= end; e += 4) {
            uint4 r0 = *(const uint4*)(feat + (size_t)srcs[e + 0] * DIM + coff);
            uint4 r1 = *(const uint4*)(feat + (size_t)srcs[e + 1] * DIM + coff);
            uint4 r2 = *(const uint4*)(feat + (size_t)srcs[e + 2] * DIM + coff);
            uint4 r3 = *(const uint4*)(feat + (size_t)srcs[e + 3] * DIM + coff);
            ACC8(r0) ACC8(r1) ACC8(r2) ACC8(r3)
        }
        for (; e < end; ++e) {
            uint4 r0 = *(const uint4*)(feat + (size_t)srcs[e] * DIM + coff);
            ACC8(r0)
        }
#undef ACC8
        float inv = 1.0f / fmaxf((float)(end - start), 1.0f);
        union { unsigned short s[8]; uint4 u; } o;
        o.s[0] = f2bf(a0 * inv); o.s[1] = f2bf(a1 * inv);
        o.s[2] = f2bf(a2 * inv); o.s[3] = f2bf(a3 * inv);
        o.s[4] = f2bf(a4 * inv); o.s[5] = f2bf(a5 * inv);
        o.s[6] = f2bf(a6 * inv); o.s[7] = f2bf(a7 * inv);
        *(uint4*)&almp[wave * 4 + q][sub * 8] = o.u;
    }
    __syncthreads();

    // ---- phase 2: MFMA (B-frags loaded per k-step from hot wbuf) ----
    int row = lane & 15;
    int kl  = (lane >> 4) << 3;
    bf16x8 A[8];
    #pragma unroll
    for (int ks = 0; ks < 4; ++ks)
        A[ks] = *(const bf16x8*)&almp[row][kl + ks * 32];
    const unsigned short* xrow = in2b + (size_t)(n0 + row) * DIM + kl;
    #pragma unroll
    for (int ks = 0; ks < 4; ++ks)
        A[4 + ks] = *(const bf16x8*)(xrow + ks * 32);

    const unsigned short* wb0 = wbuf + ((size_t)(wave * 2)     * 8 * 64 + lane) * 8;
    const unsigned short* wb1 = wbuf + ((size_t)(wave * 2 + 1) * 8 * 64 + lane) * 8;
    f32x4 acc0 = {0.f, 0.f, 0.f, 0.f}, acc1 = {0.f, 0.f, 0.f, 0.f};
    #pragma unroll
    for (int ks = 0; ks < 8; ++ks) {
        bf16x8 b0 = *(const bf16x8*)(wb0 + (size_t)ks * 64 * 8);
        bf16x8 b1 = *(const bf16x8*)(wb1 + (size_t)ks * 64 * 8);
        acc0 = __builtin_amdgcn_mfma_f32_16x16x32_bf16(A[ks], b0, acc0, 0, 0, 0);
        acc1 = __builtin_amdgcn_mfma_f32_16x16x32_bf16(A[ks], b1, acc1, 0, 0, 0);
    }

    // C/D layout: col = lane&15, row = (lane>>4)*4 + reg   [m89-verified]
    int o0   = wave * 32;
    int ocol = lane & 15;
    int rb   = (lane >> 4) << 2;
    float b0 = bias[o0 + ocol];
    float b1 = bias[o0 + 16 + ocol];

    if (POOL) {
        float v0[4], v1[4];
        #pragma unroll
        for (int r = 0; r < 4; ++r) {
            v0[r] = fmaxf(acc0[r] + b0, 0.f);
            v1[r] = fmaxf(acc1[r] + b1, 0.f);
        }
        int g0 = sb[0], g15 = sb[15];
        if (g0 == g15) {
            float s0 = v0[0] + v0[1] + v0[2] + v0[3];
            float s1 = v1[0] + v1[1] + v1[2] + v1[3];
            s0 += __shfl_xor(s0, 16); s0 += __shfl_xor(s0, 32);
            s1 += __shfl_xor(s1, 16); s1 += __shfl_xor(s1, 32);
            if (lane < 16) {
                atomicAdd(&gsum[g0 * DIM + o0 + ocol], s0);
                atomicAdd(&gsum[g0 * DIM + o0 + 16 + ocol], s1);
            }
        } else {
            #pragma unroll
            for (int r = 0; r < 4; ++r) {
                int g = sb[rb + r];
                atomicAdd(&gsum[g * DIM + o0 + ocol], v0[r]);
                atomicAdd(&gsum[g * DIM + o0 + 16 + ocol], v1[r]);
            }
        }
    } else {
        #pragma unroll
        for (int r = 0; r < 4; ++r) {
            size_t n = (size_t)(n0 + rb + r);
            outb[n * DIM + o0 + ocol]      = f2bf(fmaxf(acc0[r] + b0, 0.f));
            outb[n * DIM + o0 + 16 + ocol] = f2bf(fmaxf(acc1[r] + b1, 0.f));
        }
    }
}

// ---------------------------------------------------------------------------
// Head: per-graph mean (count via binary search on sorted batch) + MLP +
// sigmoid. One block per graph.
// ---------------------------------------------------------------------------
__global__ __launch_bounds__(256) void k_head(const float* __restrict__ gsum,
                                              const int* __restrict__ batch,
                                              const float* __restrict__ wl1,
                                              const float* __restrict__ bl1,
                                              const float* __restrict__ wout,
                                              const float* __restrict__ bout,
                                              float* __restrict__ out) {
    int g = blockIdx.x;
    int t = threadIdx.x;

    int lo = 0, hi = N_NODES;
    while (lo < hi) { int mid = (lo + hi) >> 1; if (batch[mid] < g) lo = mid + 1; else hi = mid; }
    int s = lo;
    lo = 0; hi = N_NODES;
    while (lo < hi) { int mid = (lo + hi) >> 1; if (batch[mid] < g + 1) lo = mid + 1; else hi = mid; }
    int e = lo;

    __shared__ float gvec[DIM];
    if (t < DIM) {
        float cnt = fmaxf((float)(e - s), 1.0f);
        gvec[t] = gsum[g * DIM + t] / cnt;
    }
    __syncthreads();
    if (t < 64) {
        float a = bl1[t];
        #pragma unroll 4
        for (int k = 0; k < DIM; ++k) a += wl1[t * DIM + k] * gvec[k];
        float g1 = fmaxf(a, 0.f) * wout[t];
        #pragma unroll
        for (int off = 32; off > 0; off >>= 1) g1 += __shfl_down(g1, off);
        if (t == 0) {
            float z = g1 + bout[0];
            out[g] = 1.0f / (1.0f + expf(-z));
        }
    }
}

// ---------------------------------------------------------------------------
extern "C" void kernel_launch(void* const* d_in, const int* in_sizes, int n_in,
                              void* d_out, int out_size, void* d_ws, size_t ws_size,
                              hipStream_t stream) {
    const float* x     = (const float*)d_in[0];
    const int*   ei    = (const int*)d_in[1];    // int64 in ref -> int32 here
    const int*   batch = (const int*)d_in[2];
    const float* w1l   = (const float*)d_in[3];
    const float* b1l   = (const float*)d_in[4];
    const float* w1r   = (const float*)d_in[5];
    const float* w2l   = (const float*)d_in[6];
    const float* b2l   = (const float*)d_in[7];
    const float* w2r   = (const float*)d_in[8];
    const float* wl1   = (const float*)d_in[9];
    const float* bl1   = (const float*)d_in[10];
    const float* wout  = (const float*)d_in[11];
    const float* bout  = (const float*)d_in[12];
    float* out = (float*)d_out;

    char*  wsp = (char*)d_ws;
    size_t off = 0;
    auto alloc = [&](size_t bytes) -> char* {
        char* p = wsp + off;
        off += (bytes + 255) & ~(size_t)255;
        return p;
    };
    int*  bcur = (int*)alloc((size_t)NB * NREP * BPAD * 4);
    int2* rsse = (int2*)alloc((size_t)N_NODES * 8);
    int*  srcs = (int*)alloc((size_t)NB * CAP * 4);
    unsigned* tmp = (unsigned*)alloc((size_t)NB * CAP * 4);
    unsigned short* xb    = (unsigned short*)alloc((size_t)N_NODES * DIM * 2);
    unsigned short* h1b   = (unsigned short*)alloc((size_t)N_NODES * DIM * 2);
    unsigned short* wbuf1 = (unsigned short*)alloc((size_t)8 * 8 * 64 * 8 * 2);
    unsigned short* wbuf2 = (unsigned short*)alloc((size_t)8 * 8 * 64 * 8 * 2);
    float* gsum = (float*)alloc((size_t)N_GRAPHS * DIM * 4);

    hipMemsetAsync(bcur, 0, (size_t)NB * NREP * BPAD * 4, stream);

    // fused front: edge bucketing || (bf16 convert + weight packs)
    k_front<<<NBB + NPREP, 512, 0, stream>>>(ei, bcur, tmp, x, xb,
                                             w1l, w1r, w2l, w2r, wbuf1, wbuf2);
    // local CSR over 4 segments (+ gsum zeroing)
    k_csr<<<NB, 512, 0, stream>>>(tmp, bcur, rsse, srcs, gsum);

    // conv1 (fused aggregate + GEMM)
    k_sage<0><<<N_NODES / 16, 256, 0, stream>>>(xb, xb, rsse, srcs, wbuf1, b1l,
                                                h1b, batch, gsum);
    // conv2 + fused global_mean_pool stage 1 (no h2 materialization)
    k_sage<1><<<N_NODES / 16, 256, 0, stream>>>(h1b, h1b, rsse, srcs, wbuf2, b2l,
                                                nullptr, batch, gsum);
    // head
    k_head<<<N_GRAPHS, 256, 0, stream>>>(gsum, batch, wl1, bl1, wout, bout, out);
}